// Round 2
// baseline (505.744 us; speedup 1.0000x reference)
//
#include <hip/hip_runtime.h>
#include <hip/hip_bf16.h>

// Problem: B=8, N=1024, H=2048, L=16
// out[b, tri(i,j), l] = softmax_l( s_proj[b,i,l] + e_proj[b,j,l] + b_span[l] )
// Collapse: A_s = Ws@W_start (16x2048), A_e = We@W_end; proj = x@[A_s;A_e]^T.
// All logits pre-scaled by log2(e) so softmax uses v_exp_f32 (exp2) directly.
// No atomics, no memsets: every workspace buffer is fully written before read.

#define H 2048
#define NSEQ 1024
#define NROWS 8192            // B*N
#define NPAIR 524800          // 1024*1025/2
#define LOG2E 1.4426950408889634f

// ---------------- K0a: transpose+scale W_span -> WsT[o][c], c = m*16+l ----------------
__global__ void k0a_transpose(const float* __restrict__ Wspan, float* __restrict__ WsT) {
    int idx = blockIdx.x * 256 + threadIdx.x;   // 0..16383 (float4 groups)
    int o  = idx >> 3;                          // 0..2047
    int c0 = (idx & 7) * 4;
    float v[4];
    #pragma unroll
    for (int q = 0; q < 4; ++q) {
        int c = c0 + q;
        int l = c & 15, m = c >> 4;
        v[q] = LOG2E * Wspan[l * (2 * H) + m * H + o];
    }
    *(float4*)&WsT[o * 32 + c0] = make_float4(v[0], v[1], v[2], v[3]);
}

// ------- K0b: cvec[c] = log2e*(bias_m . Wspan_m[l]) (+ log2e*b_span[l] for e-half) -----
__global__ void k0b_cvec(const float* __restrict__ b_start, const float* __restrict__ b_end,
                         const float* __restrict__ Wspan, const float* __restrict__ b_span,
                         float* __restrict__ cvec) {
    int c = blockIdx.x;                 // 0..31
    int l = c & 15, m = c >> 4;
    const float* bias = m ? b_end : b_start;
    int t = threadIdx.x;                // 64 threads = 1 wave
    float p = 0.f;
    for (int h = t; h < H; h += 64) p += bias[h] * Wspan[l * (2 * H) + m * H + h];
    #pragma unroll
    for (int off = 32; off; off >>= 1) p += __shfl_down(p, off);
    if (t == 0) cvec[c] = LOG2E * p + (m ? LOG2E * b_span[l] : 0.f);
}

// ---------------- K1a: partial A^T: p1[seg][k][l] = sum_{o in oc} WsT[o][c]*W[o][k] ----
__global__ __launch_bounds__(256) void k1a(const float* __restrict__ Wst,
                                           const float* __restrict__ Wen,
                                           const float* __restrict__ WsT,
                                           float* __restrict__ p1) {
    int blk = blockIdx.x;               // 256 = m(2) x kc(8) x oc(16)
    int m  = blk >> 7;
    int kc = (blk >> 4) & 7;
    int oc = blk & 15;
    const float* W = m ? Wen : Wst;
    int k = kc * 256 + threadIdx.x;
    float acc[16];
    #pragma unroll
    for (int i = 0; i < 16; ++i) acc[i] = 0.f;
    int o0 = oc * 128;
    for (int o = o0; o < o0 + 128; ++o) {
        float wv = W[(size_t)o * H + k];                 // coalesced over k
        const float* wsr = &WsT[o * 32 + m * 16];        // wave-uniform -> s_load
        #pragma unroll
        for (int l = 0; l < 16; ++l) acc[l] += wsr[l] * wv;
    }
    int seg = m * 16 + oc;              // 0..31
    float* dst = &p1[((size_t)seg * H + k) * 16];
    #pragma unroll
    for (int q = 0; q < 4; ++q)
        *(float4*)&dst[q * 4] = make_float4(acc[q*4], acc[q*4+1], acc[q*4+2], acc[q*4+3]);
}

// ---------------- K1b: AT[k][c] = sum_oc p1 ----------------
__global__ void k1b(const float* __restrict__ p1, float* __restrict__ AT) {
    int g = blockIdx.x * 256 + threadIdx.x;   // 16384 = 2048k x 8 cgroups
    int k  = g >> 3;
    int c0 = (g & 7) * 4;
    int m  = c0 >> 4;
    int l0 = c0 & 15;
    float sx = 0.f, sy = 0.f, sz = 0.f, sw = 0.f;
    #pragma unroll
    for (int oc = 0; oc < 16; ++oc) {
        const float* sp = &p1[(((size_t)(m * 16 + oc)) * H + k) * 16 + l0];
        float4 v = *(const float4*)sp;
        sx += v.x; sy += v.y; sz += v.z; sw += v.w;
    }
    *(float4*)&AT[(size_t)k * 32 + c0] = make_float4(sx, sy, sz, sw);
}

// ------- K2a: pp[ks][row][c] = sum_{k in ks-seg} x[row][k] * AT[k][c] ------------------
// Thread per row; AT rows wave-uniform -> SGPR operands; no LDS, no atomics.
__global__ __launch_bounds__(256) void k2a(const float* __restrict__ X,
                                           const float* __restrict__ AT,
                                           float* __restrict__ pp) {
    int blk = blockIdx.x;               // 256 = ks(8) x rg(32)
    int rg = blk & 31;
    int ks = blk >> 5;
    int t = threadIdx.x;
    int row = rg * 256 + t;
    const float* xp = X + (size_t)row * H + ks * 256;
    float acc[32];
    #pragma unroll
    for (int c = 0; c < 32; ++c) acc[c] = 0.f;
    for (int kk = 0; kk < 256; kk += 4) {
        float4 xv = *(const float4*)&xp[kk];
        const float* a = &AT[(size_t)(ks * 256 + kk) * 32];  // uniform -> s_load
        #pragma unroll
        for (int c = 0; c < 32; ++c) acc[c] += a[c] * xv.x;
        #pragma unroll
        for (int c = 0; c < 32; ++c) acc[c] += a[32 + c] * xv.y;
        #pragma unroll
        for (int c = 0; c < 32; ++c) acc[c] += a[64 + c] * xv.z;
        #pragma unroll
        for (int c = 0; c < 32; ++c) acc[c] += a[96 + c] * xv.w;
    }
    float* dst = &pp[((size_t)ks * NROWS + row) * 32];
    #pragma unroll
    for (int q = 0; q < 8; ++q)
        *(float4*)&dst[q * 4] = make_float4(acc[q*4], acc[q*4+1], acc[q*4+2], acc[q*4+3]);
}

// ---------------- K2b: proj[row][c] = sum_ks pp + cvec[c] ----------------
__global__ void k2b(const float* __restrict__ pp, const float* __restrict__ cvec,
                    float* __restrict__ proj) {
    int g = blockIdx.x * 256 + threadIdx.x;   // 65536 = 8192 rows x 8 cgroups
    int row = g >> 3;
    int c0  = (g & 7) * 4;
    float4 cv = *(const float4*)&cvec[c0];
    float sx = cv.x, sy = cv.y, sz = cv.z, sw = cv.w;
    #pragma unroll
    for (int ks = 0; ks < 8; ++ks) {
        float4 v = *(const float4*)&pp[((size_t)ks * NROWS + row) * 32 + c0];
        sx += v.x; sy += v.y; sz += v.z; sw += v.w;
    }
    *(float4*)&proj[(size_t)row * 32 + c0] = make_float4(sx, sy, sz, sw);
}

// ---------------- K3: pair softmax -> out ----------------
__global__ __launch_bounds__(256) void k3_pairs(const float* __restrict__ proj,
                                                float* __restrict__ out) {
    int blk = blockIdx.x;               // 8192 = b(8) x it(256) x jt(4)
    int b    = blk >> 10;
    int rest = blk & 1023;
    int it = rest >> 2;
    int jt = rest & 3;
    int i0 = it * 4;
    int j0 = jt * 256;
    if (j0 + 255 < i0) return;          // tile entirely below diagonal
    int t = threadIdx.x;
    int j = j0 + t;

    const float* prow = proj + ((size_t)(b * NSEQ + j) * 32 + 16);
    float ep[16];
    #pragma unroll
    for (int q = 0; q < 4; ++q) {
        float4 v = *(const float4*)&prow[q * 4];
        ep[q*4+0] = v.x; ep[q*4+1] = v.y; ep[q*4+2] = v.z; ep[q*4+3] = v.w;
    }
    size_t outB = (size_t)b * NPAIR;

    #pragma unroll
    for (int il = 0; il < 4; ++il) {
        int i = i0 + il;
        if (i > j) continue;
        const float* srow = proj + (size_t)(b * NSEQ + i) * 32;   // uniform -> s_load
        float e[16];
        #pragma unroll
        for (int c = 0; c < 16; ++c)
            e[c] = __builtin_amdgcn_exp2f(srow[c] + ep[c]);       // pre-scaled by log2e
        float s0 = (e[0] + e[1]) + (e[2] + e[3]);
        float s1 = (e[4] + e[5]) + (e[6] + e[7]);
        float s2 = (e[8] + e[9]) + (e[10] + e[11]);
        float s3 = (e[12] + e[13]) + (e[14] + e[15]);
        float r = __builtin_amdgcn_rcpf((s0 + s1) + (s2 + s3));
        size_t pidx = outB + (size_t)i * NSEQ - ((size_t)i * (i - 1)) / 2 + (size_t)(j - i);
        float* po = out + pidx * 16;
        #pragma unroll
        for (int q = 0; q < 4; ++q)
            *(float4*)&po[q * 4] = make_float4(e[q*4+0]*r, e[q*4+1]*r, e[q*4+2]*r, e[q*4+3]*r);
    }
}

extern "C" void kernel_launch(void* const* d_in, const int* in_sizes, int n_in,
                              void* d_out, int out_size, void* d_ws, size_t ws_size,
                              hipStream_t stream) {
    const float* x     = (const float*)d_in[0];
    const float* Wst   = (const float*)d_in[1];
    const float* bst   = (const float*)d_in[2];
    const float* Wen   = (const float*)d_in[3];
    const float* ben   = (const float*)d_in[4];
    const float* Wspan = (const float*)d_in[5];
    const float* bspan = (const float*)d_in[6];
    float* out = (float*)d_out;

    float* ws   = (float*)d_ws;
    float* WsT  = ws;                   //   65,536 floats
    float* cvec = ws + 65536;           //       64
    float* AT   = ws + 65600;           //   65,536
    float* p1   = ws + 131136;          // 1,048,576  (32 segs x 2048 x 16)
    float* pp   = ws + 1179712;         // 2,097,152  (8 ks x 8192 x 32)
    float* proj = ws + 3276864;         //   262,144
    // total 3,539,008 floats = 13.5 MB

    k0a_transpose<<<64, 256, 0, stream>>>(Wspan, WsT);
    k0b_cvec<<<32, 64, 0, stream>>>(bst, ben, Wspan, bspan, cvec);
    k1a<<<256, 256, 0, stream>>>(Wst, Wen, WsT, p1);
    k1b<<<64, 256, 0, stream>>>(p1, AT);
    k2a<<<256, 256, 0, stream>>>(x, AT, pp);
    k2b<<<256, 256, 0, stream>>>(pp, cvec, proj);
    k3_pairs<<<8192, 256, 0, stream>>>(proj, out);
}